// Round 1
// baseline (2424.236 us; speedup 1.0000x reference)
//
#include <hip/hip_runtime.h>
#include <math.h>

#define NNODES 10000
#define NEDGES 160000
#define E2 (NEDGES + NNODES)
#define F_IN 50
#define HIDC 350
#define NH1 4
#define NH2 4
#define NH3 6
#define OUTC 121

// ---------------- small utility kernels ----------------
__global__ void zero_int_kernel(int* p, int n) {
    int i = blockIdx.x * blockDim.x + threadIdx.x;
    if (i < n) p[i] = 0;
}
__global__ void copy_int_kernel(const int* a, int* b, int n) {
    int i = blockIdx.x * blockDim.x + threadIdx.x;
    if (i < n) b[i] = a[i];
}

// ---------------- CSR build (dst-sorted incoming edge lists) ----------------
__global__ void count_kernel(const int* __restrict__ ei, int* __restrict__ cnt) {
    int i = blockIdx.x * blockDim.x + threadIdx.x;
    if (i >= E2) return;
    int dst = (i < NEDGES) ? ei[NEDGES + i] : (i - NEDGES);
    atomicAdd(&cnt[dst], 1);
}

__global__ void scan_kernel(const int* __restrict__ cnt, int* __restrict__ indptr) {
    __shared__ int part[1024];
    int tid = threadIdx.x;
    const int CH = (NNODES + 1023) / 1024;
    int base = tid * CH;
    int s = 0;
    for (int i = 0; i < CH; i++) {
        int idx = base + i;
        if (idx < NNODES) s += cnt[idx];
    }
    part[tid] = s;
    __syncthreads();
    for (int off = 1; off < 1024; off <<= 1) {
        int v = (tid >= off) ? part[tid - off] : 0;
        __syncthreads();
        part[tid] += v;
        __syncthreads();
    }
    int run = (tid == 0) ? 0 : part[tid - 1];
    for (int i = 0; i < CH; i++) {
        int idx = base + i;
        if (idx < NNODES) {
            indptr[idx] = run;
            run += cnt[idx];
        }
    }
    if (tid == 0) indptr[NNODES] = part[1023];
}

__global__ void scatter_kernel(const int* __restrict__ ei, int* __restrict__ cursor,
                               int* __restrict__ esrc) {
    int i = blockIdx.x * blockDim.x + threadIdx.x;
    if (i >= E2) return;
    int src, dst;
    if (i < NEDGES) {
        src = ei[i];
        dst = ei[NEDGES + i];
    } else {
        src = dst = i - NEDGES;
    }
    int pos = atomicAdd(&cursor[dst], 1);
    esrc[pos] = src;
}

// ---------------- SGEMM: C[NN,M] = A[NN,K] @ B[M,K]^T (optionally += ) -----
#define GBM 128
#define GBN 128
#define GBK 8
__global__ __launch_bounds__(256) void sgemm_nt(const float* __restrict__ A,
                                                const float* __restrict__ B,
                                                float* __restrict__ C, int NN, int M,
                                                int K, int accumulate) {
    __shared__ float As[GBK][GBM + 4];
    __shared__ float Bs[GBK][GBN + 4];
    int tid = threadIdx.x;
    int tx = tid & 15, ty = tid >> 4;
    int row0 = blockIdx.y * GBM;
    int col0 = blockIdx.x * GBN;
    float acc[8][8];
#pragma unroll
    for (int i = 0; i < 8; i++)
#pragma unroll
        for (int j = 0; j < 8; j++) acc[i][j] = 0.f;

    int li = tid >> 1;       // 0..127: tile row
    int half = tid & 1;      // which float4 in k
    bool k_vec_ok = ((K & 3) == 0);

    for (int k0 = 0; k0 < K; k0 += GBK) {
        // stage A
        {
            int r = row0 + li;
            int kb = k0 + half * 4;
            float4 v = make_float4(0.f, 0.f, 0.f, 0.f);
            if (r < NN) {
                if (k_vec_ok && kb + 3 < K) {
                    v = *(const float4*)(A + (size_t)r * K + kb);
                } else {
                    float t0 = (kb + 0 < K) ? A[(size_t)r * K + kb + 0] : 0.f;
                    float t1 = (kb + 1 < K) ? A[(size_t)r * K + kb + 1] : 0.f;
                    float t2 = (kb + 2 < K) ? A[(size_t)r * K + kb + 2] : 0.f;
                    float t3 = (kb + 3 < K) ? A[(size_t)r * K + kb + 3] : 0.f;
                    v = make_float4(t0, t1, t2, t3);
                }
            }
            As[half * 4 + 0][li] = v.x;
            As[half * 4 + 1][li] = v.y;
            As[half * 4 + 2][li] = v.z;
            As[half * 4 + 3][li] = v.w;
        }
        // stage B
        {
            int r = col0 + li;
            int kb = k0 + half * 4;
            float4 v = make_float4(0.f, 0.f, 0.f, 0.f);
            if (r < M) {
                if (k_vec_ok && kb + 3 < K) {
                    v = *(const float4*)(B + (size_t)r * K + kb);
                } else {
                    float t0 = (kb + 0 < K) ? B[(size_t)r * K + kb + 0] : 0.f;
                    float t1 = (kb + 1 < K) ? B[(size_t)r * K + kb + 1] : 0.f;
                    float t2 = (kb + 2 < K) ? B[(size_t)r * K + kb + 2] : 0.f;
                    float t3 = (kb + 3 < K) ? B[(size_t)r * K + kb + 3] : 0.f;
                    v = make_float4(t0, t1, t2, t3);
                }
            }
            Bs[half * 4 + 0][li] = v.x;
            Bs[half * 4 + 1][li] = v.y;
            Bs[half * 4 + 2][li] = v.z;
            Bs[half * 4 + 3][li] = v.w;
        }
        __syncthreads();
#pragma unroll
        for (int kk = 0; kk < GBK; kk++) {
            float4 a0 = *(const float4*)&As[kk][ty * 8];
            float4 a1 = *(const float4*)&As[kk][ty * 8 + 4];
            float4 b0 = *(const float4*)&Bs[kk][tx * 8];
            float4 b1 = *(const float4*)&Bs[kk][tx * 8 + 4];
            float a[8] = {a0.x, a0.y, a0.z, a0.w, a1.x, a1.y, a1.z, a1.w};
            float b[8] = {b0.x, b0.y, b0.z, b0.w, b1.x, b1.y, b1.z, b1.w};
#pragma unroll
            for (int i = 0; i < 8; i++)
#pragma unroll
                for (int j = 0; j < 8; j++) acc[i][j] = fmaf(a[i], b[j], acc[i][j]);
        }
        __syncthreads();
    }
#pragma unroll
    for (int i = 0; i < 8; i++) {
        int r = row0 + ty * 8 + i;
        if (r >= NN) continue;
#pragma unroll
        for (int j = 0; j < 8; j++) {
            int c = col0 + tx * 8 + j;
            if (c < M) {
                size_t o = (size_t)r * M + c;
                float v = acc[i][j];
                if (accumulate) v += C[o];
                C[o] = v;
            }
        }
    }
}

// ---------------- per-node alpha_src / alpha_dst -----------------
// hpre: [N, H*C]; aw_s/aw_d: [H, C]; out as_n/ad_n: [N, H]
__global__ __launch_bounds__(256) void alpha_kernel(const float* __restrict__ hpre,
                                                    const float* __restrict__ aw_s,
                                                    const float* __restrict__ aw_d,
                                                    float* __restrict__ as_n,
                                                    float* __restrict__ ad_n, int H,
                                                    int C) {
    int n = blockIdx.x;
    int HC = H * C;
    int tid = threadIdx.x;
    __shared__ float r1[256], r2[256];
    for (int h = 0; h < H; h++) {
        float s1 = 0.f, s2 = 0.f;
        for (int c = tid; c < C; c += 256) {
            float v = hpre[(size_t)n * HC + h * C + c];
            s1 += v * aw_s[h * C + c];
            s2 += v * aw_d[h * C + c];
        }
        r1[tid] = s1;
        r2[tid] = s2;
        __syncthreads();
        for (int st = 128; st > 0; st >>= 1) {
            if (tid < st) {
                r1[tid] += r1[tid + st];
                r2[tid] += r2[tid + st];
            }
            __syncthreads();
        }
        if (tid == 0) {
            as_n[n * H + h] = r1[0];
            ad_n[n * H + h] = r2[0];
        }
        __syncthreads();
    }
}

// ---------------- softmax-weighted aggregation per dst node -----------------
// mode 0: out[n, H*C] = agg + bias  (optional ELU)
// mode 1: out[n, C]   = mean_heads(agg) + bias
#define MAXE 512
__global__ __launch_bounds__(256) void agg_kernel(
    const float* __restrict__ hpre, const float* __restrict__ as_n,
    const float* __restrict__ ad_n, const int* __restrict__ indptr,
    const int* __restrict__ esrc, const float* __restrict__ bias,
    float* __restrict__ out, int H, int C, int mode, int do_elu) {
    int n = blockIdx.x;
    int HC = H * C;
    int s = indptr[n], e = indptr[n + 1];
    int deg = e - s;
    int tid = threadIdx.x;
    __shared__ float red[256];
    __shared__ float mh[8], invs[8];
    __shared__ float wsh[MAXE * 6];
    __shared__ int srcs[MAXE];
    bool cached = (deg <= MAXE);
    if (cached) {
        for (int j = tid; j < deg; j += 256) srcs[j] = esrc[s + j];
    }
    __syncthreads();

    for (int h = 0; h < H; h++) {
        float ad = ad_n[n * H + h];
        float lm = -1e30f;
        for (int j = tid; j < deg; j += 256) {
            int sr = cached ? srcs[j] : esrc[s + j];
            float v = as_n[sr * H + h] + ad;
            v = v > 0.f ? v : 0.2f * v;
            lm = fmaxf(lm, v);
        }
        red[tid] = lm;
        __syncthreads();
        for (int st = 128; st > 0; st >>= 1) {
            if (tid < st) red[tid] = fmaxf(red[tid], red[tid + st]);
            __syncthreads();
        }
        float m = red[0];
        __syncthreads();
        float ls = 0.f;
        for (int j = tid; j < deg; j += 256) {
            int sr = cached ? srcs[j] : esrc[s + j];
            float v = as_n[sr * H + h] + ad;
            v = v > 0.f ? v : 0.2f * v;
            ls += expf(v - m);
        }
        red[tid] = ls;
        __syncthreads();
        for (int st = 128; st > 0; st >>= 1) {
            if (tid < st) red[tid] += red[tid + st];
            __syncthreads();
        }
        if (tid == 0) {
            mh[h] = m;
            invs[h] = 1.f / red[0];
        }
        __syncthreads();
    }

    if (cached) {
        for (int t = tid; t < deg * H; t += 256) {
            int j = t / H, h = t - j * H;
            float v = as_n[srcs[j] * H + h] + ad_n[n * H + h];
            v = v > 0.f ? v : 0.2f * v;
            wsh[j * H + h] = expf(v - mh[h]) * invs[h];
        }
    }
    __syncthreads();

    if (mode == 0) {
        for (int c = tid; c < HC; c += 256) {
            int h = c / C;
            float acc = 0.f;
            if (cached) {
                for (int j = 0; j < deg; j++)
                    acc = fmaf(wsh[j * H + h], hpre[(size_t)srcs[j] * HC + c], acc);
            } else {
                float ad = ad_n[n * H + h];
                for (int j = s; j < e; j++) {
                    int sr = esrc[j];
                    float v = as_n[sr * H + h] + ad;
                    v = v > 0.f ? v : 0.2f * v;
                    float w = expf(v - mh[h]) * invs[h];
                    acc = fmaf(w, hpre[(size_t)sr * HC + c], acc);
                }
            }
            acc += bias[c];
            if (do_elu) acc = acc > 0.f ? acc : expm1f(acc);
            out[(size_t)n * HC + c] = acc;
        }
    } else {
        for (int c = tid; c < C; c += 256) {
            float acc = 0.f;
            if (cached) {
                for (int j = 0; j < deg; j++) {
                    size_t base = (size_t)srcs[j] * HC;
                    for (int h = 0; h < H; h++)
                        acc = fmaf(wsh[j * H + h], hpre[base + h * C + c], acc);
                }
            } else {
                for (int j = s; j < e; j++) {
                    int sr = esrc[j];
                    size_t base = (size_t)sr * HC;
                    for (int h = 0; h < H; h++) {
                        float v = as_n[sr * H + h] + ad_n[n * H + h];
                        v = v > 0.f ? v : 0.2f * v;
                        float w = expf(v - mh[h]) * invs[h];
                        acc = fmaf(w, hpre[base + h * C + c], acc);
                    }
                }
            }
            out[(size_t)n * C + c] = acc / (float)H + bias[c];
        }
    }
}

// ---------------- launcher ----------------
extern "C" void kernel_launch(void* const* d_in, const int* in_sizes, int n_in,
                              void* d_out, int out_size, void* d_ws, size_t ws_size,
                              hipStream_t stream) {
    const float* x = (const float*)d_in[0];
    const int* ei = (const int*)d_in[1];
    const float* W1 = (const float*)d_in[2];
    const float* a1s = (const float*)d_in[3];
    const float* a1d = (const float*)d_in[4];
    const float* b1 = (const float*)d_in[5];
    const float* W2 = (const float*)d_in[6];
    const float* a2s = (const float*)d_in[7];
    const float* a2d = (const float*)d_in[8];
    const float* b2 = (const float*)d_in[9];
    const float* Wsk = (const float*)d_in[10];
    const float* W3 = (const float*)d_in[11];
    const float* a3s = (const float*)d_in[12];
    const float* a3d = (const float*)d_in[13];
    const float* b3 = (const float*)d_in[14];
    float* out = (float*)d_out;

    const size_t HC = (size_t)NH1 * HIDC;  // 1400
    char* w = (char*)d_ws;
    float* hpre = (float*)w;  w += (size_t)NNODES * HC * 4;
    float* xin = (float*)w;   w += (size_t)NNODES * HC * 4;
    float* h2 = (float*)w;    w += (size_t)NNODES * HC * 4;
    float* as_n = (float*)w;  w += (size_t)NNODES * 6 * 4;
    float* ad_n = (float*)w;  w += (size_t)NNODES * 6 * 4;
    int* cnt = (int*)w;       w += (size_t)(NNODES + 16) * 4;
    int* indptr = (int*)w;    w += (size_t)(NNODES + 16) * 4;
    int* cursor = (int*)w;    w += (size_t)(NNODES + 16) * 4;
    int* esrc = (int*)w;      w += (size_t)E2 * 4;

    // ---- CSR build ----
    zero_int_kernel<<<(NNODES + 255) / 256, 256, 0, stream>>>(cnt, NNODES);
    count_kernel<<<(E2 + 255) / 256, 256, 0, stream>>>(ei, cnt);
    scan_kernel<<<1, 1024, 0, stream>>>(cnt, indptr);
    copy_int_kernel<<<(NNODES + 255) / 256, 256, 0, stream>>>(indptr, cursor, NNODES);
    scatter_kernel<<<(E2 + 255) / 256, 256, 0, stream>>>(ei, cursor, esrc);

    dim3 blk(256);

    // ---- Layer 1 ----
    {
        int M = NH1 * HIDC, K = F_IN;
        dim3 grid((M + GBN - 1) / GBN, (NNODES + GBM - 1) / GBM);
        sgemm_nt<<<grid, blk, 0, stream>>>(x, W1, hpre, NNODES, M, K, 0);
        alpha_kernel<<<NNODES, blk, 0, stream>>>(hpre, a1s, a1d, as_n, ad_n, NH1, HIDC);
        agg_kernel<<<NNODES, blk, 0, stream>>>(hpre, as_n, ad_n, indptr, esrc, b1, xin,
                                               NH1, HIDC, 0, 1);
    }
    // ---- Layer 2 ----
    {
        int M = NH2 * HIDC, K = NH1 * HIDC;
        dim3 grid((M + GBN - 1) / GBN, (NNODES + GBM - 1) / GBM);
        sgemm_nt<<<grid, blk, 0, stream>>>(xin, W2, hpre, NNODES, M, K, 0);
        alpha_kernel<<<NNODES, blk, 0, stream>>>(hpre, a2s, a2d, as_n, ad_n, NH2, HIDC);
        agg_kernel<<<NNODES, blk, 0, stream>>>(hpre, as_n, ad_n, indptr, esrc, b2, h2,
                                               NH2, HIDC, 0, 1);
        // skip connection: h2 += xin @ Wskip^T
        sgemm_nt<<<grid, blk, 0, stream>>>(xin, Wsk, h2, NNODES, M, K, 1);
    }
    // ---- Layer 3 ----
    {
        int M = NH3 * OUTC, K = NH2 * HIDC;
        dim3 grid((M + GBN - 1) / GBN, (NNODES + GBM - 1) / GBM);
        sgemm_nt<<<grid, blk, 0, stream>>>(h2, W3, hpre, NNODES, M, K, 0);
        alpha_kernel<<<NNODES, blk, 0, stream>>>(hpre, a3s, a3d, as_n, ad_n, NH3, OUTC);
        agg_kernel<<<NNODES, blk, 0, stream>>>(hpre, as_n, ad_n, indptr, esrc, b3, out,
                                               NH3, OUTC, 1, 0);
    }
}

// Round 2
// 1722.999 us; speedup vs baseline: 1.4070x; 1.4070x over previous
//
#include <hip/hip_runtime.h>
#include <math.h>

#define NNODES 10000
#define NEDGES 160000
#define E2 (NEDGES + NNODES)
#define F_IN 50
#define HIDC 350
#define NH1 4
#define NH2 4
#define NH3 6
#define OUTC 121
#define MAXE 512

typedef __attribute__((ext_vector_type(8))) short short8;
typedef __attribute__((ext_vector_type(4))) float floatx4;

static __device__ __forceinline__ unsigned short f2bf(float f) {
    unsigned u = __float_as_uint(f);
    unsigned r = (u + 0x7fffu + ((u >> 16) & 1u)) >> 16;
    return (unsigned short)r;
}
static __device__ __forceinline__ float bf2f(unsigned short s) {
    return __uint_as_float(((unsigned)s) << 16);
}

// ---------------- small utility kernels ----------------
__global__ void zero_int_kernel(int* p, int n) {
    int i = blockIdx.x * blockDim.x + threadIdx.x;
    if (i < n) p[i] = 0;
}
__global__ void copy_int_kernel(const int* a, int* b, int n) {
    int i = blockIdx.x * blockDim.x + threadIdx.x;
    if (i < n) b[i] = a[i];
}

// ---------------- CSR build (dst-sorted incoming edge lists) ----------------
__global__ void count_kernel(const int* __restrict__ ei, int* __restrict__ cnt) {
    int i = blockIdx.x * blockDim.x + threadIdx.x;
    if (i >= E2) return;
    int dst = (i < NEDGES) ? ei[NEDGES + i] : (i - NEDGES);
    atomicAdd(&cnt[dst], 1);
}

__global__ void scan_kernel(const int* __restrict__ cnt, int* __restrict__ indptr) {
    __shared__ int part[1024];
    int tid = threadIdx.x;
    const int CH = (NNODES + 1023) / 1024;
    int base = tid * CH;
    int s = 0;
    for (int i = 0; i < CH; i++) {
        int idx = base + i;
        if (idx < NNODES) s += cnt[idx];
    }
    part[tid] = s;
    __syncthreads();
    for (int off = 1; off < 1024; off <<= 1) {
        int v = (tid >= off) ? part[tid - off] : 0;
        __syncthreads();
        part[tid] += v;
        __syncthreads();
    }
    int run = (tid == 0) ? 0 : part[tid - 1];
    for (int i = 0; i < CH; i++) {
        int idx = base + i;
        if (idx < NNODES) {
            indptr[idx] = run;
            run += cnt[idx];
        }
    }
    if (tid == 0) indptr[NNODES] = part[1023];
}

__global__ void scatter_kernel(const int* __restrict__ ei, int* __restrict__ cursor,
                               int* __restrict__ esrc) {
    int i = blockIdx.x * blockDim.x + threadIdx.x;
    if (i >= E2) return;
    int src, dst;
    if (i < NEDGES) {
        src = ei[i];
        dst = ei[NEDGES + i];
    } else {
        src = dst = i - NEDGES;
    }
    int pos = atomicAdd(&cursor[dst], 1);
    esrc[pos] = src;
}

// ---------------- split-bf16 MFMA GEMM: C[NN,M] = A[NN,K] @ B[M,K]^T ----------
// hi/lo decomposition: x ~= hi + lo with |x - hi - lo| <~ 2^-17 |x|.
// acc += ahi*bhi + alo*bhi + ahi*blo  (drops alo*blo ~ 2^-16 rel)
__global__ __launch_bounds__(256) void gemm_bt_split(const float* __restrict__ A,
                                                     const float* __restrict__ B,
                                                     float* __restrict__ C, int NN,
                                                     int M, int K, int accumulate) {
    __shared__ unsigned short Ahi[128][40];
    __shared__ unsigned short Alo[128][40];
    __shared__ unsigned short Bhi[128][40];
    __shared__ unsigned short Blo[128][40];
    int tid = threadIdx.x;
    int row0 = blockIdx.y * 128, col0 = blockIdx.x * 128;
    int r = tid >> 1, half = tid & 1;
    int wave = tid >> 6, lane = tid & 63;
    int wm = (wave >> 1) * 64, wn = (wave & 1) * 64;
    int fr = lane & 15, kq = lane >> 4;

    floatx4 acc[4][4];
#pragma unroll
    for (int i = 0; i < 4; i++)
#pragma unroll
        for (int j = 0; j < 4; j++)
#pragma unroll
            for (int q = 0; q < 4; q++) acc[i][j][q] = 0.f;

    bool kvec = ((K & 3) == 0);

    for (int k0 = 0; k0 < K; k0 += 32) {
        // ---- stage A tile ----
        {
            int gr = row0 + r;
#pragma unroll
            for (int f = 0; f < 4; ++f) {
                int kc = k0 + half * 16 + f * 4;
                float4 v = make_float4(0.f, 0.f, 0.f, 0.f);
                if (gr < NN) {
                    if (kvec && kc + 3 < K) {
                        v = *(const float4*)(A + (size_t)gr * K + kc);
                    } else {
                        if (kc + 0 < K) v.x = A[(size_t)gr * K + kc + 0];
                        if (kc + 1 < K) v.y = A[(size_t)gr * K + kc + 1];
                        if (kc + 2 < K) v.z = A[(size_t)gr * K + kc + 2];
                        if (kc + 3 < K) v.w = A[(size_t)gr * K + kc + 3];
                    }
                }
                ushort4 hi, lo;
                hi.x = f2bf(v.x); lo.x = f2bf(v.x - bf2f(hi.x));
                hi.y = f2bf(v.y); lo.y = f2bf(v.y - bf2f(hi.y));
                hi.z = f2bf(v.z); lo.z = f2bf(v.z - bf2f(hi.z));
                hi.w = f2bf(v.w); lo.w = f2bf(v.w - bf2f(hi.w));
                int col = half * 16 + f * 4;
                *(ushort4*)&Ahi[r][col] = hi;
                *(ushort4*)&Alo[r][col] = lo;
            }
        }
        // ---- stage B tile ----
        {
            int gr = col0 + r;
#pragma unroll
            for (int f = 0; f < 4; ++f) {
                int kc = k0 + half * 16 + f * 4;
                float4 v = make_float4(0.f, 0.f, 0.f, 0.f);
                if (gr < M) {
                    if (kvec && kc + 3 < K) {
                        v = *(const float4*)(B + (size_t)gr * K + kc);
                    } else {
                        if (kc + 0 < K) v.x = B[(size_t)gr * K + kc + 0];
                        if (kc + 1 < K) v.y = B[(size_t)gr * K + kc + 1];
                        if (kc + 2 < K) v.z = B[(size_t)gr * K + kc + 2];
                        if (kc + 3 < K) v.w = B[(size_t)gr * K + kc + 3];
                    }
                }
                ushort4 hi, lo;
                hi.x = f2bf(v.x); lo.x = f2bf(v.x - bf2f(hi.x));
                hi.y = f2bf(v.y); lo.y = f2bf(v.y - bf2f(hi.y));
                hi.z = f2bf(v.z); lo.z = f2bf(v.z - bf2f(hi.z));
                hi.w = f2bf(v.w); lo.w = f2bf(v.w - bf2f(hi.w));
                int col = half * 16 + f * 4;
                *(ushort4*)&Bhi[r][col] = hi;
                *(ushort4*)&Blo[r][col] = lo;
            }
        }
        __syncthreads();

        short8 ah[4], al[4], bh[4], bl[4];
#pragma unroll
        for (int i = 0; i < 4; i++) {
            ah[i] = *(const short8*)&Ahi[wm + i * 16 + fr][kq * 8];
            al[i] = *(const short8*)&Alo[wm + i * 16 + fr][kq * 8];
            bh[i] = *(const short8*)&Bhi[wn + i * 16 + fr][kq * 8];
            bl[i] = *(const short8*)&Blo[wn + i * 16 + fr][kq * 8];
        }
#pragma unroll
        for (int i = 0; i < 4; i++)
#pragma unroll
            for (int j = 0; j < 4; j++) {
                acc[i][j] = __builtin_amdgcn_mfma_f32_16x16x32_bf16(ah[i], bh[j],
                                                                   acc[i][j], 0, 0, 0);
                acc[i][j] = __builtin_amdgcn_mfma_f32_16x16x32_bf16(al[i], bh[j],
                                                                   acc[i][j], 0, 0, 0);
                acc[i][j] = __builtin_amdgcn_mfma_f32_16x16x32_bf16(ah[i], bl[j],
                                                                   acc[i][j], 0, 0, 0);
            }
        __syncthreads();
    }

    // ---- epilogue: C/D layout col=lane&15, row=(lane>>4)*4+reg ----
#pragma unroll
    for (int i = 0; i < 4; i++) {
#pragma unroll
        for (int rg = 0; rg < 4; rg++) {
            int rr = row0 + wm + i * 16 + kq * 4 + rg;
            if (rr >= NN) continue;
#pragma unroll
            for (int j = 0; j < 4; j++) {
                int cc = col0 + wn + j * 16 + fr;
                if (cc < M) {
                    size_t o = (size_t)rr * M + cc;
                    float vv = acc[i][j][rg];
                    if (accumulate) vv += C[o];
                    C[o] = vv;
                }
            }
        }
    }
}

// ---------------- per-node alpha_src / alpha_dst: one wave per node ----------
template <int H, int C>
__global__ __launch_bounds__(256) void alpha2(const float* __restrict__ hpre,
                                              const float* __restrict__ aws,
                                              const float* __restrict__ awd,
                                              float* __restrict__ as_n,
                                              float* __restrict__ ad_n) {
    int tid = threadIdx.x;
    int wave = tid >> 6, lane = tid & 63;
    int n = blockIdx.x * 4 + wave;
    if (n >= NNODES) return;
    const float* row = hpre + (size_t)n * H * C;
#pragma unroll
    for (int h = 0; h < H; h++) {
        float s1 = 0.f, s2 = 0.f;
        for (int c = lane; c < C; c += 64) {
            float v = row[h * C + c];
            s1 = fmaf(v, aws[h * C + c], s1);
            s2 = fmaf(v, awd[h * C + c], s2);
        }
#pragma unroll
        for (int o = 32; o > 0; o >>= 1) {
            s1 += __shfl_xor(s1, o, 64);
            s2 += __shfl_xor(s2, o, 64);
        }
        if (lane == 0) {
            as_n[n * H + h] = s1;
            ad_n[n * H + h] = s2;
        }
    }
}

// ---------------- softmax-weighted aggregation, one block per dst node -------
// MODE 0: out[n, H*C] = agg + bias (optional ELU)
// MODE 1: out[n, C]   = mean_heads(agg) + bias
template <int H, int C, int MODE, int DOELU>
__global__ __launch_bounds__(256) void agg2(const float* __restrict__ hpre,
                                            const float* __restrict__ as_n,
                                            const float* __restrict__ ad_n,
                                            const int* __restrict__ indptr,
                                            const int* __restrict__ esrc,
                                            const float* __restrict__ bias,
                                            float* __restrict__ out) {
    constexpr int HC = H * C;
    int n = blockIdx.x;
    int tid = threadIdx.x;
    int s = indptr[n], e = indptr[n + 1];
    int deg = e - s;
    if (deg > MAXE) deg = MAXE;  // safety (never hit for this graph)

    __shared__ int srcs[MAXE];
    __shared__ float wgt[MAXE * H];
    __shared__ float aggsh[MODE ? HC : 1];

    // ---- phase 1: softmax weights, wave 0 only, shuffle reductions ----
    if (tid < 64) {
        int lane = tid;
        float adv[H], mx[H], sm[H];
#pragma unroll
        for (int h = 0; h < H; h++) {
            adv[h] = ad_n[n * H + h];
            mx[h] = -1e30f;
            sm[h] = 0.f;
        }
        for (int j = lane; j < deg; j += 64) {
            int sr = esrc[s + j];
            srcs[j] = sr;
#pragma unroll
            for (int h = 0; h < H; h++) {
                float ev = as_n[sr * H + h] + adv[h];
                ev = ev > 0.f ? ev : 0.2f * ev;
                wgt[j * H + h] = ev;
                mx[h] = fmaxf(mx[h], ev);
            }
        }
#pragma unroll
        for (int h = 0; h < H; h++)
#pragma unroll
            for (int o = 32; o > 0; o >>= 1) mx[h] = fmaxf(mx[h], __shfl_xor(mx[h], o, 64));
        for (int j = lane; j < deg; j += 64) {
#pragma unroll
            for (int h = 0; h < H; h++) {
                float p = __expf(wgt[j * H + h] - mx[h]);
                wgt[j * H + h] = p;
                sm[h] += p;
            }
        }
#pragma unroll
        for (int h = 0; h < H; h++) {
#pragma unroll
            for (int o = 32; o > 0; o >>= 1) sm[h] += __shfl_xor(sm[h], o, 64);
            sm[h] = 1.f / sm[h];
        }
        for (int j = lane; j < deg; j += 64) {
#pragma unroll
            for (int h = 0; h < H; h++) wgt[j * H + h] *= sm[h];
        }
    }
    __syncthreads();

    // ---- phase 2: weighted gather over channels ----
    if (MODE == 0) {
        constexpr int NV4 = HC / 4;  // HC divisible by 4 for layers 1/2 (1400)
        for (int c4 = tid; c4 < NV4; c4 += 256) {
            int cb = c4 * 4;
            int h0 = (cb + 0) / C, h1 = (cb + 1) / C;
            int h2c = (cb + 2) / C, h3 = (cb + 3) / C;
            float ax = 0.f, ay = 0.f, az = 0.f, aw = 0.f;
            for (int j = 0; j < deg; ++j) {
                const float4 v = *(const float4*)(hpre + (size_t)srcs[j] * HC + cb);
                const float* wj = &wgt[j * H];
                ax = fmaf(wj[h0], v.x, ax);
                ay = fmaf(wj[h1], v.y, ay);
                az = fmaf(wj[h2c], v.z, az);
                aw = fmaf(wj[h3], v.w, aw);
            }
            ax += bias[cb + 0];
            ay += bias[cb + 1];
            az += bias[cb + 2];
            aw += bias[cb + 3];
            if (DOELU) {
                ax = ax > 0.f ? ax : expm1f(ax);
                ay = ay > 0.f ? ay : expm1f(ay);
                az = az > 0.f ? az : expm1f(az);
                aw = aw > 0.f ? aw : expm1f(aw);
            }
            float4 res = make_float4(ax, ay, az, aw);
            *(float4*)(out + (size_t)n * HC + cb) = res;
        }
    } else {
        for (int cc = tid; cc < HC; cc += 256) {
            int h = cc / C;
            float a = 0.f;
            for (int j = 0; j < deg; ++j)
                a = fmaf(wgt[j * H + h], hpre[(size_t)srcs[j] * HC + cc], a);
            aggsh[cc] = a;
        }
        __syncthreads();
        for (int c = tid; c < C; c += 256) {
            float sres = 0.f;
#pragma unroll
            for (int h = 0; h < H; h++) sres += aggsh[h * C + c];
            out[(size_t)n * C + c] = sres * (1.f / (float)H) + bias[c];
        }
    }
}

// ---------------- launcher ----------------
extern "C" void kernel_launch(void* const* d_in, const int* in_sizes, int n_in,
                              void* d_out, int out_size, void* d_ws, size_t ws_size,
                              hipStream_t stream) {
    const float* x = (const float*)d_in[0];
    const int* ei = (const int*)d_in[1];
    const float* W1 = (const float*)d_in[2];
    const float* a1s = (const float*)d_in[3];
    const float* a1d = (const float*)d_in[4];
    const float* b1 = (const float*)d_in[5];
    const float* W2 = (const float*)d_in[6];
    const float* a2s = (const float*)d_in[7];
    const float* a2d = (const float*)d_in[8];
    const float* b2 = (const float*)d_in[9];
    const float* Wsk = (const float*)d_in[10];
    const float* W3 = (const float*)d_in[11];
    const float* a3s = (const float*)d_in[12];
    const float* a3d = (const float*)d_in[13];
    const float* b3 = (const float*)d_in[14];
    float* out = (float*)d_out;

    const size_t HC = (size_t)NH1 * HIDC;  // 1400
    char* w = (char*)d_ws;
    float* hpre = (float*)w;  w += (size_t)NNODES * HC * 4;
    float* xin = (float*)w;   w += (size_t)NNODES * HC * 4;
    float* h2 = (float*)w;    w += (size_t)NNODES * HC * 4;
    float* as_n = (float*)w;  w += (size_t)NNODES * 6 * 4;
    float* ad_n = (float*)w;  w += (size_t)NNODES * 6 * 4;
    int* cnt = (int*)w;       w += (size_t)(NNODES + 16) * 4;
    int* indptr = (int*)w;    w += (size_t)(NNODES + 16) * 4;
    int* cursor = (int*)w;    w += (size_t)(NNODES + 16) * 4;
    int* esrc = (int*)w;      w += (size_t)E2 * 4;

    // ---- CSR build ----
    zero_int_kernel<<<(NNODES + 255) / 256, 256, 0, stream>>>(cnt, NNODES);
    count_kernel<<<(E2 + 255) / 256, 256, 0, stream>>>(ei, cnt);
    scan_kernel<<<1, 1024, 0, stream>>>(cnt, indptr);
    copy_int_kernel<<<(NNODES + 255) / 256, 256, 0, stream>>>(indptr, cursor, NNODES);
    scatter_kernel<<<(E2 + 255) / 256, 256, 0, stream>>>(ei, cursor, esrc);

    dim3 blk(256);
    int gy = (NNODES + 127) / 128;  // 79

    // ---- Layer 1 ----
    {
        int M = NH1 * HIDC, K = F_IN;
        dim3 grid((M + 127) / 128, gy);
        gemm_bt_split<<<grid, blk, 0, stream>>>(x, W1, hpre, NNODES, M, K, 0);
        alpha2<NH1, HIDC><<<(NNODES + 3) / 4, blk, 0, stream>>>(hpre, a1s, a1d, as_n, ad_n);
        agg2<NH1, HIDC, 0, 1><<<NNODES, blk, 0, stream>>>(hpre, as_n, ad_n, indptr,
                                                          esrc, b1, xin);
    }
    // ---- Layer 2 ----
    {
        int M = NH2 * HIDC, K = NH1 * HIDC;
        dim3 grid((M + 127) / 128, gy);
        gemm_bt_split<<<grid, blk, 0, stream>>>(xin, W2, hpre, NNODES, M, K, 0);
        alpha2<NH2, HIDC><<<(NNODES + 3) / 4, blk, 0, stream>>>(hpre, a2s, a2d, as_n, ad_n);
        agg2<NH2, HIDC, 0, 1><<<NNODES, blk, 0, stream>>>(hpre, as_n, ad_n, indptr,
                                                          esrc, b2, h2);
        // skip connection: h2 += xin @ Wskip^T
        gemm_bt_split<<<grid, blk, 0, stream>>>(xin, Wsk, h2, NNODES, M, K, 1);
    }
    // ---- Layer 3 ----
    {
        int M = NH3 * OUTC, K = NH2 * HIDC;
        dim3 grid((M + 127) / 128, gy);
        gemm_bt_split<<<grid, blk, 0, stream>>>(h2, W3, hpre, NNODES, M, K, 0);
        alpha2<NH3, OUTC><<<(NNODES + 3) / 4, blk, 0, stream>>>(hpre, a3s, a3d, as_n, ad_n);
        agg2<NH3, OUTC, 1, 0><<<NNODES, blk, 0, stream>>>(hpre, as_n, ad_n, indptr,
                                                          esrc, b3, out);
    }
}

// Round 3
// 917.734 us; speedup vs baseline: 2.6415x; 1.8774x over previous
//
#include <hip/hip_runtime.h>
#include <math.h>

#define NNODES 10000
#define NEDGES 160000
#define E2 (NEDGES + NNODES)
#define F_IN 50
#define HIDC 350
#define NH1 4
#define NH2 4
#define NH3 6
#define OUTC 121
#define MAXE 512
#define KP1 64      // F_IN=50 padded to 64
#define KP2 1408    // 1400 padded to 1408
#define ROWSLACK 128

typedef __attribute__((ext_vector_type(8))) short short8;
typedef __attribute__((ext_vector_type(4))) float floatx4;

static __device__ __forceinline__ unsigned short f2bf(float f) {
    unsigned u = __float_as_uint(f);
    unsigned r = (u + 0x7fffu + ((u >> 16) & 1u)) >> 16;
    return (unsigned short)r;
}
static __device__ __forceinline__ float bf2f(unsigned short s) {
    return __uint_as_float(((unsigned)s) << 16);
}

// async global->LDS, 16 bytes per lane; LDS dest must be wave-uniform base + lane*16
#define GLL16(gp, lp)                                                      \
    __builtin_amdgcn_global_load_lds(                                      \
        (const __attribute__((address_space(1))) void*)(gp),               \
        (__attribute__((address_space(3))) void*)(lp), 16, 0, 0)

// ---------------- small utility kernels ----------------
__global__ void zero_int_kernel(int* p, int n) {
    int i = blockIdx.x * blockDim.x + threadIdx.x;
    if (i < n) p[i] = 0;
}
__global__ void copy_int_kernel(const int* a, int* b, int n) {
    int i = blockIdx.x * blockDim.x + threadIdx.x;
    if (i < n) b[i] = a[i];
}

// ---------------- CSR build (dst-sorted incoming edge lists) ----------------
__global__ void count_kernel(const int* __restrict__ ei, int* __restrict__ cnt) {
    int i = blockIdx.x * blockDim.x + threadIdx.x;
    if (i >= E2) return;
    int dst = (i < NEDGES) ? ei[NEDGES + i] : (i - NEDGES);
    atomicAdd(&cnt[dst], 1);
}

__global__ void scan_kernel(const int* __restrict__ cnt, int* __restrict__ indptr) {
    __shared__ int part[1024];
    int tid = threadIdx.x;
    const int CH = (NNODES + 1023) / 1024;
    int base = tid * CH;
    int s = 0;
    for (int i = 0; i < CH; i++) {
        int idx = base + i;
        if (idx < NNODES) s += cnt[idx];
    }
    part[tid] = s;
    __syncthreads();
    for (int off = 1; off < 1024; off <<= 1) {
        int v = (tid >= off) ? part[tid - off] : 0;
        __syncthreads();
        part[tid] += v;
        __syncthreads();
    }
    int run = (tid == 0) ? 0 : part[tid - 1];
    for (int i = 0; i < CH; i++) {
        int idx = base + i;
        if (idx < NNODES) {
            indptr[idx] = run;
            run += cnt[idx];
        }
    }
    if (tid == 0) indptr[NNODES] = part[1023];
}

__global__ void scatter_kernel(const int* __restrict__ ei, int* __restrict__ cursor,
                               int* __restrict__ esrc) {
    int i = blockIdx.x * blockDim.x + threadIdx.x;
    if (i >= E2) return;
    int src, dst;
    if (i < NEDGES) {
        src = ei[i];
        dst = ei[NEDGES + i];
    } else {
        src = dst = i - NEDGES;
    }
    int pos = atomicAdd(&cursor[dst], 1);
    esrc[pos] = src;
}

// ---------------- fp32 -> bf16 hi/lo split with K padding ----------------
__global__ void split_pad_kernel(const float* __restrict__ src,
                                 unsigned short* __restrict__ hi,
                                 unsigned short* __restrict__ lo, int K, int Kp,
                                 int row_off) {
    int k = blockIdx.x * blockDim.x + threadIdx.x;
    int r = blockIdx.y;
    if (k >= Kp) return;
    float v = (k < K) ? src[(size_t)r * K + k] : 0.f;
    unsigned short h = f2bf(v);
    hi[(size_t)(row_off + r) * Kp + k] = h;
    lo[(size_t)(row_off + r) * Kp + k] = f2bf(v - bf2f(h));
}

// ---------------- split-bf16 MFMA GEMM, pre-split operands ----------------
// C[NN, M] = (Ahi+Alo) @ (Bhi+Blo)^T  (3-product split), row stride ldc.
// Tiles staged via global_load_lds with XOR group swizzle (bank-conflict-free).
__global__ __launch_bounds__(256) void gemm_hilo(const unsigned short* __restrict__ Ahi,
                                                 const unsigned short* __restrict__ Alo,
                                                 const unsigned short* __restrict__ Bhi,
                                                 const unsigned short* __restrict__ Blo,
                                                 float* __restrict__ C, int NN, int M,
                                                 int Kp, int ldc) {
    __shared__ __align__(16) unsigned short sA[2][128 * 32];
    __shared__ __align__(16) unsigned short sB[2][128 * 32];
    int tid = threadIdx.x;
    int wave = tid >> 6, lane = tid & 63;
    int wm = (wave >> 1) * 64, wn = (wave & 1) * 64;
    int fr = lane & 15, kq = lane >> 4;
    int row0 = blockIdx.y * 128, col0 = blockIdx.x * 128;

    floatx4 acc[4][4];
#pragma unroll
    for (int i = 0; i < 4; i++)
#pragma unroll
        for (int j = 0; j < 4; j++)
#pragma unroll
            for (int q = 0; q < 4; q++) acc[i][j][q] = 0.f;

    // staging geometry: wave w covers tile rows [w*32, w*32+32), two 16-row chunks
    int gpos = lane & 3;
    int r0c = wave * 32 + (lane >> 2);  // chunk0 row; chunk1 = +16
    int gsw = kq ^ ((fr >> 1) & 3);     // fragment-read swizzled group

    for (int k0 = 0; k0 < Kp; k0 += 32) {
#pragma unroll
        for (int c = 0; c < 2; ++c) {
            int r = r0c + c * 16;
            int g = gpos ^ ((r >> 1) & 3);  // global k-group stored at position gpos
            size_t gofs_a = (size_t)(row0 + r) * Kp + k0 + g * 8;
            size_t gofs_b = (size_t)(col0 + r) * Kp + k0 + g * 8;
            size_t lofs = (size_t)r * 32 + (size_t)gpos * 8;
            GLL16(Ahi + gofs_a, &sA[0][lofs]);
            GLL16(Alo + gofs_a, &sA[1][lofs]);
            GLL16(Bhi + gofs_b, &sB[0][lofs]);
            GLL16(Blo + gofs_b, &sB[1][lofs]);
        }
        __syncthreads();

        short8 ah[4], al[4], bh[4], bl[4];
#pragma unroll
        for (int i = 0; i < 4; i++) {
            int ra = wm + i * 16 + fr, rb = wn + i * 16 + fr;
            ah[i] = *(const short8*)&sA[0][ra * 32 + gsw * 8];
            al[i] = *(const short8*)&sA[1][ra * 32 + gsw * 8];
            bh[i] = *(const short8*)&sB[0][rb * 32 + gsw * 8];
            bl[i] = *(const short8*)&sB[1][rb * 32 + gsw * 8];
        }
#pragma unroll
        for (int i = 0; i < 4; i++)
#pragma unroll
            for (int j = 0; j < 4; j++) {
                acc[i][j] = __builtin_amdgcn_mfma_f32_16x16x32_bf16(ah[i], bh[j],
                                                                   acc[i][j], 0, 0, 0);
                acc[i][j] = __builtin_amdgcn_mfma_f32_16x16x32_bf16(al[i], bh[j],
                                                                   acc[i][j], 0, 0, 0);
                acc[i][j] = __builtin_amdgcn_mfma_f32_16x16x32_bf16(ah[i], bl[j],
                                                                   acc[i][j], 0, 0, 0);
            }
        __syncthreads();
    }

    // C/D layout: col=lane&15, row=(lane>>4)*4+reg
#pragma unroll
    for (int i = 0; i < 4; i++) {
#pragma unroll
        for (int rg = 0; rg < 4; rg++) {
            int rr = row0 + wm + i * 16 + kq * 4 + rg;
            if (rr >= NN) continue;
#pragma unroll
            for (int j = 0; j < 4; j++) {
                int cc = col0 + wn + j * 16 + fr;
                if (cc < M) C[(size_t)rr * ldc + cc] = acc[i][j][rg];
            }
        }
    }
}

// ---------------- per-node alpha_src / alpha_dst: one wave per node ----------
template <int H, int C>
__global__ __launch_bounds__(256) void alpha2(const float* __restrict__ hpre, int ldh,
                                              const float* __restrict__ aws,
                                              const float* __restrict__ awd,
                                              float* __restrict__ as_n,
                                              float* __restrict__ ad_n) {
    int tid = threadIdx.x;
    int wave = tid >> 6, lane = tid & 63;
    int n = blockIdx.x * 4 + wave;
    if (n >= NNODES) return;
    const float* row = hpre + (size_t)n * ldh;
#pragma unroll
    for (int h = 0; h < H; h++) {
        float s1 = 0.f, s2 = 0.f;
        for (int c = lane; c < C; c += 64) {
            float v = row[h * C + c];
            s1 = fmaf(v, aws[h * C + c], s1);
            s2 = fmaf(v, awd[h * C + c], s2);
        }
#pragma unroll
        for (int o = 32; o > 0; o >>= 1) {
            s1 += __shfl_xor(s1, o, 64);
            s2 += __shfl_xor(s2, o, 64);
        }
        if (lane == 0) {
            as_n[n * H + h] = s1;
            ad_n[n * H + h] = s2;
        }
    }
}

// ---------------- softmax-weighted aggregation, one block per dst node -------
// MODE 0: v = agg + bias (+ELU) (+skip); emit bf16 hi/lo into outHi/outLo[n*Kp]
// MODE 1: outF[n, C] = mean_heads(agg) + bias (fp32)
template <int H, int C, int MODE, int DOELU, int SKIP>
__global__ __launch_bounds__(256) void agg2(
    const float* __restrict__ hpre, int ldh, const float* __restrict__ skip,
    const float* __restrict__ as_n, const float* __restrict__ ad_n,
    const int* __restrict__ indptr, const int* __restrict__ esrc,
    const float* __restrict__ bias, unsigned short* __restrict__ outHi,
    unsigned short* __restrict__ outLo, int Kp, float* __restrict__ outF) {
    constexpr int HC = H * C;
    int n = blockIdx.x;
    int tid = threadIdx.x;
    int s = indptr[n], e = indptr[n + 1];
    int deg = e - s;
    if (deg > MAXE) deg = MAXE;  // safety (never hit for this graph)

    __shared__ int srcs[MAXE];
    __shared__ float wgt[MAXE * H];
    __shared__ float aggsh[MODE ? HC : 1];

    // ---- phase 1: softmax weights, wave 0 only, shuffle reductions ----
    if (tid < 64) {
        int lane = tid;
        float adv[H], mx[H], sm[H];
#pragma unroll
        for (int h = 0; h < H; h++) {
            adv[h] = ad_n[n * H + h];
            mx[h] = -1e30f;
            sm[h] = 0.f;
        }
        for (int j = lane; j < deg; j += 64) {
            int sr = esrc[s + j];
            srcs[j] = sr;
#pragma unroll
            for (int h = 0; h < H; h++) {
                float ev = as_n[sr * H + h] + adv[h];
                ev = ev > 0.f ? ev : 0.2f * ev;
                wgt[j * H + h] = ev;
                mx[h] = fmaxf(mx[h], ev);
            }
        }
#pragma unroll
        for (int h = 0; h < H; h++)
#pragma unroll
            for (int o = 32; o > 0; o >>= 1) mx[h] = fmaxf(mx[h], __shfl_xor(mx[h], o, 64));
        for (int j = lane; j < deg; j += 64) {
#pragma unroll
            for (int h = 0; h < H; h++) {
                float p = __expf(wgt[j * H + h] - mx[h]);
                wgt[j * H + h] = p;
                sm[h] += p;
            }
        }
#pragma unroll
        for (int h = 0; h < H; h++) {
#pragma unroll
            for (int o = 32; o > 0; o >>= 1) sm[h] += __shfl_xor(sm[h], o, 64);
            sm[h] = 1.f / sm[h];
        }
        for (int j = lane; j < deg; j += 64) {
#pragma unroll
            for (int h = 0; h < H; h++) wgt[j * H + h] *= sm[h];
        }
    }
    __syncthreads();

    // ---- phase 2: weighted gather over channels ----
    if (MODE == 0) {
        constexpr int NV4 = HC / 4;
        for (int c4 = tid; c4 < NV4; c4 += 256) {
            int cb = c4 * 4;
            int h0 = (cb + 0) / C, h1 = (cb + 1) / C;
            int h2c = (cb + 2) / C, h3 = (cb + 3) / C;
            float ax = 0.f, ay = 0.f, az = 0.f, aw = 0.f;
            for (int j = 0; j < deg; ++j) {
                const float4 v = *(const float4*)(hpre + (size_t)srcs[j] * ldh + cb);
                const float* wj = &wgt[j * H];
                ax = fmaf(wj[h0], v.x, ax);
                ay = fmaf(wj[h1], v.y, ay);
                az = fmaf(wj[h2c], v.z, az);
                aw = fmaf(wj[h3], v.w, aw);
            }
            ax += bias[cb + 0];
            ay += bias[cb + 1];
            az += bias[cb + 2];
            aw += bias[cb + 3];
            if (DOELU) {
                ax = ax > 0.f ? ax : expm1f(ax);
                ay = ay > 0.f ? ay : expm1f(ay);
                az = az > 0.f ? az : expm1f(az);
                aw = aw > 0.f ? aw : expm1f(aw);
            }
            if (SKIP) {
                const float4 sk = *(const float4*)(skip + (size_t)n * ldh + cb);
                ax += sk.x;
                ay += sk.y;
                az += sk.z;
                aw += sk.w;
            }
            ushort4 hi4, lo4;
            hi4.x = f2bf(ax); lo4.x = f2bf(ax - bf2f(hi4.x));
            hi4.y = f2bf(ay); lo4.y = f2bf(ay - bf2f(hi4.y));
            hi4.z = f2bf(az); lo4.z = f2bf(az - bf2f(hi4.z));
            hi4.w = f2bf(aw); lo4.w = f2bf(aw - bf2f(hi4.w));
            *(ushort4*)(outHi + (size_t)n * Kp + cb) = hi4;
            *(ushort4*)(outLo + (size_t)n * Kp + cb) = lo4;
        }
        // zero K padding columns
        for (int c = HC + tid; c < Kp; c += 256) {
            outHi[(size_t)n * Kp + c] = 0;
            outLo[(size_t)n * Kp + c] = 0;
        }
    } else {
        for (int cc = tid; cc < HC; cc += 256) {
            int h = cc / C;
            float a = 0.f;
            for (int j = 0; j < deg; ++j)
                a = fmaf(wgt[j * H + h], hpre[(size_t)srcs[j] * ldh + cc], a);
            aggsh[cc] = a;
        }
        __syncthreads();
        for (int c = tid; c < C; c += 256) {
            float sres = 0.f;
#pragma unroll
            for (int h = 0; h < H; h++) sres += aggsh[h * C + c];
            outF[(size_t)n * C + c] = sres * (1.f / (float)H) + bias[c];
        }
    }
}

// ---------------- launcher ----------------
extern "C" void kernel_launch(void* const* d_in, const int* in_sizes, int n_in,
                              void* d_out, int out_size, void* d_ws, size_t ws_size,
                              hipStream_t stream) {
    const float* x = (const float*)d_in[0];
    const int* ei = (const int*)d_in[1];
    const float* W1 = (const float*)d_in[2];
    const float* a1s = (const float*)d_in[3];
    const float* a1d = (const float*)d_in[4];
    const float* b1 = (const float*)d_in[5];
    const float* W2 = (const float*)d_in[6];
    const float* a2s = (const float*)d_in[7];
    const float* a2d = (const float*)d_in[8];
    const float* b2 = (const float*)d_in[9];
    const float* Wsk = (const float*)d_in[10];
    const float* W3 = (const float*)d_in[11];
    const float* a3s = (const float*)d_in[12];
    const float* a3d = (const float*)d_in[13];
    const float* b3 = (const float*)d_in[14];
    float* out = (float*)d_out;

    char* w = (char*)d_ws;
    size_t off = 0;
    auto alloc = [&](size_t bytes) -> char* {
        char* p = w + off;
        off += (bytes + 255) & ~(size_t)255;
        return p;
    };
    float* hpre = (float*)alloc((size_t)NNODES * 2800 * 4);                       // 112 MB
    unsigned short* actHi = (unsigned short*)alloc((size_t)(NNODES + ROWSLACK) * KP2 * 2);
    unsigned short* actLo = (unsigned short*)alloc((size_t)(NNODES + ROWSLACK) * KP2 * 2);
    unsigned short* xHi = (unsigned short*)alloc((size_t)(NNODES + ROWSLACK) * KP1 * 2);
    unsigned short* xLo = (unsigned short*)alloc((size_t)(NNODES + ROWSLACK) * KP1 * 2);
    unsigned short* wHi = (unsigned short*)alloc((size_t)(2800 + ROWSLACK) * KP2 * 2);
    unsigned short* wLo = (unsigned short*)alloc((size_t)(2800 + ROWSLACK) * KP2 * 2);
    float* as_n = (float*)alloc((size_t)NNODES * 6 * 4);
    float* ad_n = (float*)alloc((size_t)NNODES * 6 * 4);
    int* cnt = (int*)alloc((size_t)(NNODES + 16) * 4);
    int* indptr = (int*)alloc((size_t)(NNODES + 16) * 4);
    int* cursor = (int*)alloc((size_t)(NNODES + 16) * 4);
    int* esrc = (int*)alloc((size_t)E2 * 4);

    // ---- CSR build ----
    zero_int_kernel<<<(NNODES + 255) / 256, 256, 0, stream>>>(cnt, NNODES);
    count_kernel<<<(E2 + 255) / 256, 256, 0, stream>>>(ei, cnt);
    scan_kernel<<<1, 1024, 0, stream>>>(cnt, indptr);
    copy_int_kernel<<<(NNODES + 255) / 256, 256, 0, stream>>>(indptr, cursor, NNODES);
    scatter_kernel<<<(E2 + 255) / 256, 256, 0, stream>>>(ei, cursor, esrc);

    dim3 blk(256);
    int gy = (NNODES + 127) / 128;  // 79

    // ---- Layer 1 ----
    {
        split_pad_kernel<<<dim3(1, NNODES), 64, 0, stream>>>(x, xHi, xLo, F_IN, KP1, 0);
        split_pad_kernel<<<dim3(1, NH1 * HIDC), 64, 0, stream>>>(W1, wHi, wLo, F_IN, KP1, 0);
        int M = NH1 * HIDC;
        dim3 grid((M + 127) / 128, gy);
        gemm_hilo<<<grid, blk, 0, stream>>>(xHi, xLo, wHi, wLo, hpre, NNODES, M, KP1, M);
        alpha2<NH1, HIDC><<<(NNODES + 3) / 4, blk, 0, stream>>>(hpre, M, a1s, a1d, as_n, ad_n);
        agg2<NH1, HIDC, 0, 1, 0><<<NNODES, blk, 0, stream>>>(
            hpre, M, nullptr, as_n, ad_n, indptr, esrc, b1, actHi, actLo, KP2, nullptr);
    }
    // ---- Layer 2 (fused with skip: B = [W2; Wskip], M = 2800) ----
    {
        int HC = NH2 * HIDC;  // 1400
        split_pad_kernel<<<dim3((KP2 + 255) / 256, HC), 256, 0, stream>>>(W2, wHi, wLo, HC, KP2, 0);
        split_pad_kernel<<<dim3((KP2 + 255) / 256, HC), 256, 0, stream>>>(Wsk, wHi, wLo, HC, KP2, HC);
        int M = 2 * HC;  // 2800
        dim3 grid((M + 127) / 128, gy);
        gemm_hilo<<<grid, blk, 0, stream>>>(actHi, actLo, wHi, wLo, hpre, NNODES, M, KP2, M);
        alpha2<NH2, HIDC><<<(NNODES + 3) / 4, blk, 0, stream>>>(hpre, M, a2s, a2d, as_n, ad_n);
        agg2<NH2, HIDC, 0, 1, 1><<<NNODES, blk, 0, stream>>>(
            hpre, M, hpre + HC, as_n, ad_n, indptr, esrc, b2, actHi, actLo, KP2, nullptr);
    }
    // ---- Layer 3 ----
    {
        int M = NH3 * OUTC;  // 726
        split_pad_kernel<<<dim3((KP2 + 255) / 256, M), 256, 0, stream>>>(W3, wHi, wLo, NH2 * HIDC, KP2, 0);
        dim3 grid((M + 127) / 128, gy);
        gemm_hilo<<<grid, blk, 0, stream>>>(actHi, actLo, wHi, wLo, hpre, NNODES, M, KP2, M);
        alpha2<NH3, OUTC><<<(NNODES + 3) / 4, blk, 0, stream>>>(hpre, M, a3s, a3d, as_n, ad_n);
        agg2<NH3, OUTC, 1, 0, 0><<<NNODES, blk, 0, stream>>>(
            hpre, M, nullptr, as_n, ad_n, indptr, esrc, b3, nullptr, nullptr, 0, out);
    }
}

// Round 4
// 888.724 us; speedup vs baseline: 2.7278x; 1.0326x over previous
//
#include <hip/hip_runtime.h>
#include <math.h>

#define NNODES 10000
#define NEDGES 160000
#define E2 (NEDGES + NNODES)
#define F_IN 50
#define HIDC 350
#define NH1 4
#define NH2 4
#define NH3 6
#define OUTC 121
#define MAXE 512
#define KP1 64      // F_IN=50 padded to 64
#define KP2 1408    // 1400 padded to 1408
#define ROWSLACK 128

typedef __attribute__((ext_vector_type(8))) short short8;
typedef __attribute__((ext_vector_type(4))) float floatx4;

static __device__ __forceinline__ unsigned short f2bf(float f) {
    unsigned u = __float_as_uint(f);
    unsigned r = (u + 0x7fffu + ((u >> 16) & 1u)) >> 16;
    return (unsigned short)r;
}
static __device__ __forceinline__ float bf2f(unsigned short s) {
    return __uint_as_float(((unsigned)s) << 16);
}

// async global->LDS, 16 bytes per lane; LDS dest is wave-uniform base + lane*16
#define GLL16(gp, lp)                                                      \
    __builtin_amdgcn_global_load_lds(                                      \
        (const __attribute__((address_space(1))) void*)(gp),               \
        (__attribute__((address_space(3))) void*)(lp), 16, 0, 0)

// ---------------- CSR build (dst-sorted incoming edge lists) ----------------
__global__ void count_kernel(const int* __restrict__ ei, int* __restrict__ cnt) {
    int i = blockIdx.x * blockDim.x + threadIdx.x;
    if (i >= E2) return;
    int dst = (i < NEDGES) ? ei[NEDGES + i] : (i - NEDGES);
    atomicAdd(&cnt[dst], 1);
}

// exclusive scan; writes both indptr and cursor
__global__ void scan_kernel(const int* __restrict__ cnt, int* __restrict__ indptr,
                            int* __restrict__ cursor) {
    __shared__ int part[1024];
    int tid = threadIdx.x;
    const int CH = (NNODES + 1023) / 1024;
    int base = tid * CH;
    int s = 0;
    for (int i = 0; i < CH; i++) {
        int idx = base + i;
        if (idx < NNODES) s += cnt[idx];
    }
    part[tid] = s;
    __syncthreads();
    for (int off = 1; off < 1024; off <<= 1) {
        int v = (tid >= off) ? part[tid - off] : 0;
        __syncthreads();
        part[tid] += v;
        __syncthreads();
    }
    int run = (tid == 0) ? 0 : part[tid - 1];
    for (int i = 0; i < CH; i++) {
        int idx = base + i;
        if (idx < NNODES) {
            indptr[idx] = run;
            cursor[idx] = run;
            run += cnt[idx];
        }
    }
    if (tid == 0) indptr[NNODES] = part[1023];
}

__global__ void scatter_kernel(const int* __restrict__ ei, int* __restrict__ cursor,
                               int* __restrict__ esrc) {
    int i = blockIdx.x * blockDim.x + threadIdx.x;
    if (i >= E2) return;
    int src, dst;
    if (i < NEDGES) {
        src = ei[i];
        dst = ei[NEDGES + i];
    } else {
        src = dst = i - NEDGES;
    }
    int pos = atomicAdd(&cursor[dst], 1);
    esrc[pos] = src;
}

// ---------------- fused fp32 -> bf16 hi/lo splits ----------------
// Kp=64 jobs: rows 0..NNODES-1 = x, then 1400 rows of W1
__global__ void splitA_kernel(const float* __restrict__ x, const float* __restrict__ W1,
                              unsigned short* __restrict__ xHi, unsigned short* __restrict__ xLo,
                              unsigned short* __restrict__ w1Hi, unsigned short* __restrict__ w1Lo) {
    int k = threadIdx.x;  // 0..63
    int r = blockIdx.y;
    const float* src;
    unsigned short *hi, *lo;
    int row;
    if (r < NNODES) { src = x; row = r; hi = xHi; lo = xLo; }
    else { src = W1; row = r - NNODES; hi = w1Hi; lo = w1Lo; }
    float v = (k < F_IN) ? src[(size_t)row * F_IN + k] : 0.f;
    unsigned short h = f2bf(v);
    hi[(size_t)row * KP1 + k] = h;
    lo[(size_t)row * KP1 + k] = f2bf(v - bf2f(h));
}

// Kp=1408 jobs: rows 0..1399 = W2, 1400..2799 = Wskip (into w2 planes), 2800.. = W3
__global__ void splitB_kernel(const float* __restrict__ W2, const float* __restrict__ Wsk,
                              const float* __restrict__ W3,
                              unsigned short* __restrict__ w2Hi, unsigned short* __restrict__ w2Lo,
                              unsigned short* __restrict__ w3Hi, unsigned short* __restrict__ w3Lo) {
    int k = blockIdx.x * blockDim.x + threadIdx.x;
    if (k >= KP2) return;
    int r = blockIdx.y;
    const int K = 1400;
    const float* src;
    unsigned short *hi, *lo;
    int row;
    if (r < 1400) { src = W2; row = r; hi = w2Hi; lo = w2Lo; }
    else if (r < 2800) { src = Wsk; row = r - 1400; hi = w2Hi + (size_t)1400 * KP2; lo = w2Lo + (size_t)1400 * KP2; }
    else { src = W3; row = r - 2800; hi = w3Hi; lo = w3Lo; }
    float v = (k < K) ? src[(size_t)row * K + k] : 0.f;
    unsigned short h = f2bf(v);
    hi[(size_t)row * KP2 + k] = h;
    lo[(size_t)row * KP2 + k] = f2bf(v - bf2f(h));
}

// ---------------- split-bf16 MFMA GEMM, 128x256 tile ----------------
// C[NN, M] = (Ahi+Alo) @ (Bhi+Blo)^T (3-product split), row stride ldc.
__global__ __launch_bounds__(256, 2) void gemm_hilo(
    const unsigned short* __restrict__ Ahi, const unsigned short* __restrict__ Alo,
    const unsigned short* __restrict__ Bhi, const unsigned short* __restrict__ Blo,
    float* __restrict__ C, int NN, int M, int Kp, int ldc) {
    __shared__ __align__(16) unsigned short sA[2][128 * 32];
    __shared__ __align__(16) unsigned short sB[2][256 * 32];
    int tid = threadIdx.x;
    int wave = tid >> 6, lane = tid & 63;
    int wm = (wave >> 1) * 64, wn = (wave & 1) * 128;
    int fr = lane & 15, kq = lane >> 4;
    int row0 = blockIdx.y * 128, col0 = blockIdx.x * 256;

    floatx4 acc[4][8];
#pragma unroll
    for (int i = 0; i < 4; i++)
#pragma unroll
        for (int j = 0; j < 8; j++)
#pragma unroll
            for (int q = 0; q < 4; q++) acc[i][j][q] = 0.f;

    int gpos = lane & 3;
    int rl = lane >> 2;                 // 0..15 staging row within chunk
    int gsw = kq ^ ((fr >> 1) & 3);     // fragment-read swizzled group

    for (int k0 = 0; k0 < Kp; k0 += 32) {
        // A: 128 rows, 8 chunks of 16; 2 chunks per wave
#pragma unroll
        for (int c = 0; c < 2; ++c) {
            int r = wave * 32 + c * 16 + rl;
            int g = gpos ^ ((r >> 1) & 3);
            size_t gofs = (size_t)(row0 + r) * Kp + k0 + g * 8;
            size_t lofs = (size_t)r * 32 + (size_t)gpos * 8;
            GLL16(Ahi + gofs, &sA[0][lofs]);
            GLL16(Alo + gofs, &sA[1][lofs]);
        }
        // B: 256 rows, 16 chunks of 16; 4 chunks per wave
#pragma unroll
        for (int c = 0; c < 4; ++c) {
            int r = wave * 64 + c * 16 + rl;
            int g = gpos ^ ((r >> 1) & 3);
            size_t gofs = (size_t)(col0 + r) * Kp + k0 + g * 8;
            size_t lofs = (size_t)r * 32 + (size_t)gpos * 8;
            GLL16(Bhi + gofs, &sB[0][lofs]);
            GLL16(Blo + gofs, &sB[1][lofs]);
        }
        __syncthreads();

        short8 ah[4], al[4], bh[8], bl[8];
#pragma unroll
        for (int j = 0; j < 8; j++) {
            int rb = wn + j * 16 + fr;
            bh[j] = *(const short8*)&sB[0][rb * 32 + gsw * 8];
            bl[j] = *(const short8*)&sB[1][rb * 32 + gsw * 8];
        }
#pragma unroll
        for (int i = 0; i < 4; i++) {
            int ra = wm + i * 16 + fr;
            ah[i] = *(const short8*)&sA[0][ra * 32 + gsw * 8];
            al[i] = *(const short8*)&sA[1][ra * 32 + gsw * 8];
        }
#pragma unroll
        for (int i = 0; i < 4; i++)
#pragma unroll
            for (int j = 0; j < 8; j++) {
                acc[i][j] = __builtin_amdgcn_mfma_f32_16x16x32_bf16(ah[i], bh[j],
                                                                   acc[i][j], 0, 0, 0);
                acc[i][j] = __builtin_amdgcn_mfma_f32_16x16x32_bf16(al[i], bh[j],
                                                                   acc[i][j], 0, 0, 0);
                acc[i][j] = __builtin_amdgcn_mfma_f32_16x16x32_bf16(ah[i], bl[j],
                                                                   acc[i][j], 0, 0, 0);
            }
        __syncthreads();
    }

    // C/D layout: col=lane&15, row=(lane>>4)*4+reg
#pragma unroll
    for (int i = 0; i < 4; i++) {
#pragma unroll
        for (int rg = 0; rg < 4; rg++) {
            int rr = row0 + wm + i * 16 + kq * 4 + rg;
            if (rr >= NN) continue;
#pragma unroll
            for (int j = 0; j < 8; j++) {
                int cc = col0 + wn + j * 16 + fr;
                if (cc < M) C[(size_t)rr * ldc + cc] = acc[i][j][rg];
            }
        }
    }
}

// ---------------- per-node alpha_src / alpha_dst: one wave per node ----------
template <int H, int C>
__global__ __launch_bounds__(256) void alpha2(const float* __restrict__ hpre, int ldh,
                                              const float* __restrict__ aws,
                                              const float* __restrict__ awd,
                                              float* __restrict__ as_n,
                                              float* __restrict__ ad_n) {
    int tid = threadIdx.x;
    int wave = tid >> 6, lane = tid & 63;
    int n = blockIdx.x * 4 + wave;
    if (n >= NNODES) return;
    const float* row = hpre + (size_t)n * ldh;
#pragma unroll
    for (int h = 0; h < H; h++) {
        float s1 = 0.f, s2 = 0.f;
        for (int c = lane; c < C; c += 64) {
            float v = row[h * C + c];
            s1 = fmaf(v, aws[h * C + c], s1);
            s2 = fmaf(v, awd[h * C + c], s2);
        }
#pragma unroll
        for (int o = 32; o > 0; o >>= 1) {
            s1 += __shfl_xor(s1, o, 64);
            s2 += __shfl_xor(s2, o, 64);
        }
        if (lane == 0) {
            as_n[n * H + h] = s1;
            ad_n[n * H + h] = s2;
        }
    }
}

// ---------------- softmax-weighted aggregation, one block per dst node -------
// MODE 0: v = agg + bias (+ELU) (+skip); emit bf16 hi/lo into outHi/outLo[n*Kp]
// MODE 1: outF[n, C] = mean_heads(agg) + bias (fp32)
#define AGG_T 384
template <int H, int C, int MODE, int DOELU, int SKIP>
__global__ __launch_bounds__(AGG_T) void agg2(
    const float* __restrict__ hpre, int ldh, const float* __restrict__ skip,
    const float* __restrict__ as_n, const float* __restrict__ ad_n,
    const int* __restrict__ indptr, const int* __restrict__ esrc,
    const float* __restrict__ bias, unsigned short* __restrict__ outHi,
    unsigned short* __restrict__ outLo, int Kp, float* __restrict__ outF) {
    constexpr int HC = H * C;
    int n = blockIdx.x;
    int tid = threadIdx.x;
    int s = indptr[n], e = indptr[n + 1];
    int deg = e - s;
    if (deg > MAXE) deg = MAXE;  // safety (never hit for this graph)

    __shared__ int srcs[MAXE];
    __shared__ float wgt[MAXE * H];
    __shared__ float aggsh[MODE ? HC : 1];

    // ---- phase 1: softmax weights, wave 0 only, shuffle reductions ----
    if (tid < 64) {
        int lane = tid;
        float adv[H], mx[H], sm[H];
#pragma unroll
        for (int h = 0; h < H; h++) {
            adv[h] = ad_n[n * H + h];
            mx[h] = -1e30f;
            sm[h] = 0.f;
        }
        for (int j = lane; j < deg; j += 64) {
            int sr = esrc[s + j];
            srcs[j] = sr;
#pragma unroll
            for (int h = 0; h < H; h++) {
                float ev = as_n[sr * H + h] + adv[h];
                ev = ev > 0.f ? ev : 0.2f * ev;
                wgt[j * H + h] = ev;
                mx[h] = fmaxf(mx[h], ev);
            }
        }
#pragma unroll
        for (int h = 0; h < H; h++)
#pragma unroll
            for (int o = 32; o > 0; o >>= 1) mx[h] = fmaxf(mx[h], __shfl_xor(mx[h], o, 64));
        for (int j = lane; j < deg; j += 64) {
#pragma unroll
            for (int h = 0; h < H; h++) {
                float p = __expf(wgt[j * H + h] - mx[h]);
                wgt[j * H + h] = p;
                sm[h] += p;
            }
        }
#pragma unroll
        for (int h = 0; h < H; h++) {
#pragma unroll
            for (int o = 32; o > 0; o >>= 1) sm[h] += __shfl_xor(sm[h], o, 64);
            sm[h] = 1.f / sm[h];
        }
        for (int j = lane; j < deg; j += 64) {
#pragma unroll
            for (int h = 0; h < H; h++) wgt[j * H + h] *= sm[h];
        }
    }
    __syncthreads();

    // ---- phase 2: weighted gather over channels ----
    if (MODE == 0) {
        constexpr int NV4 = HC / 4;
        for (int c4 = tid; c4 < NV4; c4 += AGG_T) {
            int cb = c4 * 4;
            int h0 = (cb + 0) / C, h1 = (cb + 1) / C;
            int h2c = (cb + 2) / C, h3 = (cb + 3) / C;
            float ax = 0.f, ay = 0.f, az = 0.f, aw = 0.f;
            int j = 0;
            for (; j + 1 < deg; j += 2) {
                const float4 v0 = *(const float4*)(hpre + (size_t)srcs[j] * ldh + cb);
                const float4 v1 = *(const float4*)(hpre + (size_t)srcs[j + 1] * ldh + cb);
                const float* w0 = &wgt[j * H];
                const float* w1 = &wgt[(j + 1) * H];
                ax = fmaf(w0[h0], v0.x, ax);
                ay = fmaf(w0[h1], v0.y, ay);
                az = fmaf(w0[h2c], v0.z, az);
                aw = fmaf(w0[h3], v0.w, aw);
                ax = fmaf(w1[h0], v1.x, ax);
                ay = fmaf(w1[h1], v1.y, ay);
                az = fmaf(w1[h2c], v1.z, az);
                aw = fmaf(w1[h3], v1.w, aw);
            }
            if (j < deg) {
                const float4 v0 = *(const float4*)(hpre + (size_t)srcs[j] * ldh + cb);
                const float* w0 = &wgt[j * H];
                ax = fmaf(w0[h0], v0.x, ax);
                ay = fmaf(w0[h1], v0.y, ay);
                az = fmaf(w0[h2c], v0.z, az);
                aw = fmaf(w0[h3], v0.w, aw);
            }
            ax += bias[cb + 0];
            ay += bias[cb + 1];
            az += bias[cb + 2];
            aw += bias[cb + 3];
            if (DOELU) {
                ax = ax > 0.f ? ax : expm1f(ax);
                ay = ay > 0.f ? ay : expm1f(ay);
                az = az > 0.f ? az : expm1f(az);
                aw = aw > 0.f ? aw : expm1f(aw);
            }
            if (SKIP) {
                const float4 sk = *(const float4*)(skip + (size_t)n * ldh + cb);
                ax += sk.x;
                ay += sk.y;
                az += sk.z;
                aw += sk.w;
            }
            ushort4 hi4, lo4;
            hi4.x = f2bf(ax); lo4.x = f2bf(ax - bf2f(hi4.x));
            hi4.y = f2bf(ay); lo4.y = f2bf(ay - bf2f(hi4.y));
            hi4.z = f2bf(az); lo4.z = f2bf(az - bf2f(hi4.z));
            hi4.w = f2bf(aw); lo4.w = f2bf(aw - bf2f(hi4.w));
            *(ushort4*)(outHi + (size_t)n * Kp + cb) = hi4;
            *(ushort4*)(outLo + (size_t)n * Kp + cb) = lo4;
        }
        // zero K padding columns
        for (int c = HC + tid; c < Kp; c += AGG_T) {
            outHi[(size_t)n * Kp + c] = 0;
            outLo[(size_t)n * Kp + c] = 0;
        }
    } else {
        for (int cc = tid; cc < HC; cc += AGG_T) {
            int h = cc / C;
            float a = 0.f;
            for (int j = 0; j < deg; ++j)
                a = fmaf(wgt[j * H + h], hpre[(size_t)srcs[j] * ldh + cc], a);
            aggsh[cc] = a;
        }
        __syncthreads();
        for (int c = tid; c < C; c += AGG_T) {
            float sres = 0.f;
#pragma unroll
            for (int h = 0; h < H; h++) sres += aggsh[h * C + c];
            outF[(size_t)n * C + c] = sres * (1.f / (float)H) + bias[c];
        }
    }
}

// ---------------- launcher ----------------
extern "C" void kernel_launch(void* const* d_in, const int* in_sizes, int n_in,
                              void* d_out, int out_size, void* d_ws, size_t ws_size,
                              hipStream_t stream) {
    const float* x = (const float*)d_in[0];
    const int* ei = (const int*)d_in[1];
    const float* W1 = (const float*)d_in[2];
    const float* a1s = (const float*)d_in[3];
    const float* a1d = (const float*)d_in[4];
    const float* b1 = (const float*)d_in[5];
    const float* W2 = (const float*)d_in[6];
    const float* a2s = (const float*)d_in[7];
    const float* a2d = (const float*)d_in[8];
    const float* b2 = (const float*)d_in[9];
    const float* Wsk = (const float*)d_in[10];
    const float* W3 = (const float*)d_in[11];
    const float* a3s = (const float*)d_in[12];
    const float* a3d = (const float*)d_in[13];
    const float* b3 = (const float*)d_in[14];
    float* out = (float*)d_out;

    char* w = (char*)d_ws;
    size_t off = 0;
    auto alloc = [&](size_t bytes) -> char* {
        char* p = w + off;
        off += (bytes + 255) & ~(size_t)255;
        return p;
    };
    float* hpre = (float*)alloc((size_t)NNODES * 2800 * 4);
    unsigned short* actHi = (unsigned short*)alloc((size_t)(NNODES + ROWSLACK) * KP2 * 2);
    unsigned short* actLo = (unsigned short*)alloc((size_t)(NNODES + ROWSLACK) * KP2 * 2);
    unsigned short* xHi = (unsigned short*)alloc((size_t)(NNODES + ROWSLACK) * KP1 * 2);
    unsigned short* xLo = (unsigned short*)alloc((size_t)(NNODES + ROWSLACK) * KP1 * 2);
    unsigned short* w1Hi = (unsigned short*)alloc((size_t)(1400 + ROWSLACK) * KP1 * 2);
    unsigned short* w1Lo = (unsigned short*)alloc((size_t)(1400 + ROWSLACK) * KP1 * 2);
    unsigned short* w2Hi = (unsigned short*)alloc((size_t)(2800 + ROWSLACK) * KP2 * 2);
    unsigned short* w2Lo = (unsigned short*)alloc((size_t)(2800 + ROWSLACK) * KP2 * 2);
    unsigned short* w3Hi = (unsigned short*)alloc((size_t)(726 + ROWSLACK) * KP2 * 2);
    unsigned short* w3Lo = (unsigned short*)alloc((size_t)(726 + ROWSLACK) * KP2 * 2);
    float* as_n = (float*)alloc((size_t)NNODES * 6 * 4);
    float* ad_n = (float*)alloc((size_t)NNODES * 6 * 4);
    int* cnt = (int*)alloc((size_t)(NNODES + 16) * 4);
    int* indptr = (int*)alloc((size_t)(NNODES + 16) * 4);
    int* cursor = (int*)alloc((size_t)(NNODES + 16) * 4);
    int* esrc = (int*)alloc((size_t)E2 * 4);

    // ---- weight/input hi-lo splits (fused) ----
    splitA_kernel<<<dim3(1, NNODES + 1400), 64, 0, stream>>>(x, W1, xHi, xLo, w1Hi, w1Lo);
    splitB_kernel<<<dim3(6, 2800 + 726), 256, 0, stream>>>(W2, Wsk, W3, w2Hi, w2Lo,
                                                           w3Hi, w3Lo);

    // ---- CSR build ----
    hipMemsetAsync(cnt, 0, NNODES * sizeof(int), stream);
    count_kernel<<<(E2 + 255) / 256, 256, 0, stream>>>(ei, cnt);
    scan_kernel<<<1, 1024, 0, stream>>>(cnt, indptr, cursor);
    scatter_kernel<<<(E2 + 255) / 256, 256, 0, stream>>>(ei, cursor, esrc);

    dim3 blk(256);
    int gy = (NNODES + 127) / 128;  // 79

    // ---- Layer 1 ----
    {
        int M = NH1 * HIDC;  // 1400
        dim3 grid((M + 255) / 256, gy);
        gemm_hilo<<<grid, blk, 0, stream>>>(xHi, xLo, w1Hi, w1Lo, hpre, NNODES, M, KP1, M);
        alpha2<NH1, HIDC><<<(NNODES + 3) / 4, blk, 0, stream>>>(hpre, M, a1s, a1d, as_n, ad_n);
        agg2<NH1, HIDC, 0, 1, 0><<<NNODES, AGG_T, 0, stream>>>(
            hpre, M, nullptr, as_n, ad_n, indptr, esrc, b1, actHi, actLo, KP2, nullptr);
    }
    // ---- Layer 2 (fused with skip: B = [W2; Wskip], M = 2800) ----
    {
        int HC = NH2 * HIDC;  // 1400
        int M = 2 * HC;       // 2800
        dim3 grid((M + 255) / 256, gy);
        gemm_hilo<<<grid, blk, 0, stream>>>(actHi, actLo, w2Hi, w2Lo, hpre, NNODES, M, KP2, M);
        alpha2<NH2, HIDC><<<(NNODES + 3) / 4, blk, 0, stream>>>(hpre, M, a2s, a2d, as_n, ad_n);
        agg2<NH2, HIDC, 0, 1, 1><<<NNODES, AGG_T, 0, stream>>>(
            hpre, M, hpre + HC, as_n, ad_n, indptr, esrc, b2, actHi, actLo, KP2, nullptr);
    }
    // ---- Layer 3 ----
    {
        int M = NH3 * OUTC;  // 726
        dim3 grid((M + 255) / 256, gy);
        gemm_hilo<<<grid, blk, 0, stream>>>(actHi, actLo, w3Hi, w3Lo, hpre, NNODES, M, KP2, M);
        alpha2<NH3, OUTC><<<(NNODES + 3) / 4, blk, 0, stream>>>(hpre, M, a3s, a3d, as_n, ad_n);
        agg2<NH3, OUTC, 1, 0, 0><<<NNODES, AGG_T, 0, stream>>>(
            hpre, M, nullptr, as_n, ad_n, indptr, esrc, b3, nullptr, nullptr, 0, out);
    }
}